// Round 1
// baseline (7401.608 us; speedup 1.0000x reference)
//
#include <hip/hip_runtime.h>
#include <hip/hip_cooperative_groups.h>

namespace cg = cooperative_groups;

// Problem constants (match reference setup_inputs)
constexpr int L = 64;
constexpr int P = 32768;
constexpr int N = L * P;          // 2,097,152 nodes
constexpr int E_PER = 262144;     // edges per non-source level
constexpr int NLEVELS = L - 1;    // 63 edge levels

// Wavefront longest-path:
//   out = hdr (all zeros in practice)
//   for l in 0..62:  out[dst] = max(out[dst], out[src]+1) via atomicMax
// dst of level l lies in [ (l+1)*P, (l+2)*P ), src in [0, (l+1)*P ) -- so
// reads and atomic writes within a level are disjoint; levels are ordered
// by grid.sync() (ROCm cooperative grid sync includes device-scope
// release/acquire fences -> L2 writeback/invalidate across XCDs).
//
// All h values are non-negative floats, so atomicMax on the uint bit
// pattern is order-equivalent to float max.
__global__ void __launch_bounds__(256, 4)
pathfinder_kernel(const float* __restrict__ hdr,
                  const int* __restrict__ src,
                  const int* __restrict__ dst,
                  float* __restrict__ out) {
    cg::grid_group grid = cg::this_grid();

    const int tid = blockIdx.x * blockDim.x + threadIdx.x;
    const int nthreads = gridDim.x * blockDim.x;

    // init out = hdr (d_out is poisoned 0xAA before every timed launch)
    for (int i = tid; i < N; i += nthreads) {
        out[i] = hdr[i];
    }
    grid.sync();

    for (int l = 0; l < NLEVELS; ++l) {
        const int* __restrict__ s = src + (size_t)l * E_PER;
        const int* __restrict__ d = dst + (size_t)l * E_PER;
        for (int e = tid; e < E_PER; e += nthreads) {
            const int si = s[e];
            const int di = d[e];
            const float v = out[si] + 1.0f;
            atomicMax((unsigned int*)&out[di], __float_as_uint(v));
        }
        grid.sync();
    }
}

extern "C" void kernel_launch(void* const* d_in, const int* in_sizes, int n_in,
                              void* d_out, int out_size, void* d_ws, size_t ws_size,
                              hipStream_t stream) {
    const float* hdr = (const float*)d_in[0];
    const int*   src = (const int*)d_in[1];
    const int*   dst = (const int*)d_in[2];
    float*       out = (float*)d_out;

    // 1024 blocks x 256 threads = 262144 threads (1 edge/thread/level).
    // 4 blocks/CU (16 waves/CU), no LDS, low VGPR -> safely co-resident
    // for cooperative launch on 256 CUs.
    void* args[] = {(void*)&hdr, (void*)&src, (void*)&dst, (void*)&out};
    hipLaunchCooperativeKernel((void*)pathfinder_kernel,
                               dim3(1024), dim3(256), args, 0, stream);
}

// Round 2
// 943.107 us; speedup vs baseline: 7.8481x; 7.8481x over previous
//
#include <hip/hip_runtime.h>

// Problem constants (match reference setup_inputs)
constexpr int L = 64;
constexpr int P = 32768;
constexpr int N = L * P;          // 2,097,152 nodes
constexpr int E_PER = 262144;     // edges per non-source level
constexpr int NLEVELS = L - 1;    // 63 edge levels

// out = hdr; N/4 float4s, one per thread (N/4 = 524288 = 2048 blocks * 256)
__global__ void __launch_bounds__(256)
init_kernel(const float4* __restrict__ hdr, float4* __restrict__ out) {
    const int i = blockIdx.x * blockDim.x + threadIdx.x;
    out[i] = hdr[i];
}

// One level of wavefront longest-path: out[d[e]] = max(out[d[e]], out[s[e]]+1).
// All h values non-negative floats -> atomicMax on uint bit pattern is exact.
// Atomic result is unused (fire-and-forget); stream ordering between launches
// provides the level->level dependency and cross-XCD visibility.
__global__ void __launch_bounds__(256)
level_kernel(const int* __restrict__ s, const int* __restrict__ d,
             float* __restrict__ out) {
    const int e = blockIdx.x * blockDim.x + threadIdx.x;   // E_PER = 1024*256 exactly
    const int si = s[e];
    const int di = d[e];
    const float v = out[si] + 1.0f;
    atomicMax((unsigned int*)out + di, __float_as_uint(v));
}

extern "C" void kernel_launch(void* const* d_in, const int* in_sizes, int n_in,
                              void* d_out, int out_size, void* d_ws, size_t ws_size,
                              hipStream_t stream) {
    const float* hdr = (const float*)d_in[0];
    const int*   src = (const int*)d_in[1];
    const int*   dst = (const int*)d_in[2];
    float*       out = (float*)d_out;

    // init: out = hdr (d_out is re-poisoned before every timed launch)
    init_kernel<<<dim3(N / 4 / 256), dim3(256), 0, stream>>>(
        (const float4*)hdr, (float4*)out);

    // 63 dependent level kernels; stream order replaces grid.sync
    for (int l = 0; l < NLEVELS; ++l) {
        level_kernel<<<dim3(E_PER / 256), dim3(256), 0, stream>>>(
            src + (size_t)l * E_PER, dst + (size_t)l * E_PER, out);
    }
}